// Round 10
// baseline (361.795 us; speedup 1.0000x reference)
//
#include <hip/hip_runtime.h>
#include <math.h>

// Capsule dynamic routing, MI355X. Round 13 (2nd resubmit; R8/R9 benches were
// broker acquisition timeouts, kernel never ran): cut route's LDS-pipe instr ~2x.
// R12 post-mortem: barrier cut was neutral -> route is LDS-pipe instr-bound
// (~150 LDS ops/lane: 40 V-broadcasts, 32 b64 u-reads, 24 Cs reads, shfls).
// R13 route:
//   - V read from GLOBAL (5KB/batch, shared by 64 blocks -> L2-hot; lesson:
//     don't LDS-stage what L2-fits). -40 LDS reads/lane, -5KB LDS, -6 DMA.
//   - ph2 re-laned: lane=(c4 column, row-half). u: 16 b128 (was 32 b64);
//     Cs: 12 b128 (was 24); 12-shfl half-fold; G stored DIRECT to global
//     (coalesced b128, LDS G-buffer deleted).
//   - LDS 17.25KB -> 8 blocks/CU (wave cap) via __launch_bounds__(256,8).
// iter0/fold unchanged (verified R11/R12). Chain:
// iter0(Sp) -> fold0(V) -> route(Gp) -> fold1(V) -> route(Gp) -> fold2(out).

#define BATCH 64
#define NN    2048
#define KD    128
#define JCAP  10
#define DCAP  16
#define JDIM  160
#define EPSQ  1e-7f
#define NT    64      // tiles of TROW rows ; NT*TROW == NN
#define TROW  32

// ws layout (floats): Gp[64][64][10][128] @0 (Sp[64][64][128] aliases @0) ;
//                     V[64][10][128] @5242880
#define WS_GP 0
#define WS_V  (BATCH * NT * JCAP * KD)

__device__ __forceinline__ void gload16(const float* g, void* l) {
  __builtin_amdgcn_global_load_lds(
      (const __attribute__((address_space(1))) void*)g,
      (__attribute__((address_space(3))) void*)l, 16, 0, 0);
}

// ---- K1: per-tile colsum partials Sp[b][tile][k] ----
__global__ __launch_bounds__(256) void f_iter0(const float* __restrict__ u,
                                               float* __restrict__ Sp) {
  const int b = blockIdx.y, tile = blockIdx.x, t = threadIdx.x;
  __shared__ __align__(16) float4 red[256];
  const int c = t & 31, rg = t >> 5;        // 8 row-groups x 4 rows
  const float* p = u + (((size_t)(b * NN + tile * TROW + rg * 4)) << 7) + (c << 2);
  float4 a = make_float4(0.f, 0.f, 0.f, 0.f);
#pragma unroll
  for (int r = 0; r < 4; ++r) {
    const float4 w4 = *(const float4*)(p + ((size_t)r << 7));
    a.x += w4.x; a.y += w4.y; a.z += w4.z; a.w += w4.w;
  }
  red[t] = a;
  __syncthreads();
  if (t < 32) {
    float4 s4 = red[t];
#pragma unroll
    for (int g = 1; g < 8; ++g) {
      const float4 w4 = red[g * 32 + t];
      s4.x += w4.x; s4.y += w4.y; s4.z += w4.z; s4.w += w4.w;
    }
    *(float4*)&Sp[(size_t)(b * NT + tile) * KD + t * 4] = s4;
  }
}

// ---- K2/K4/K6: block (j,b): fold partials -> o[j] -> {V | squash-out} ----
// pass0: In=Sp (x0.1) ; pass1: In=Gp ; both write V. pass2: In=Gp, write out.
__global__ __launch_bounds__(128) void f_fold(const float* __restrict__ In,
                                              const float* __restrict__ W,
                                              float* __restrict__ Out, int pass) {
  const int j = blockIdx.x, b = blockIdx.y, t = threadIdx.x;
  __shared__ float g_s[KD];
  __shared__ float o_s[DCAP];
  if (pass == 0) {
    const float* p = In + (size_t)b * NT * KD + t;        // Sp[b][tl][t]
    float s = 0.f;
#pragma unroll 8
    for (int tl = 0; tl < NT; ++tl) s += p[(size_t)tl * KD];
    g_s[t] = s * 0.1f;
  } else {
    const float* p = In + ((size_t)(b * NT) * JCAP + j) * KD + t;  // Gp[b][tl][j][t]
    float s = 0.f;
#pragma unroll 8
    for (int tl = 0; tl < NT; ++tl) s += p[(size_t)tl * JCAP * KD];
    g_s[t] = s;
  }
  __syncthreads();
  if (t < DCAP) {
    // o[j][d] = sum_k G[j][k] * W[k][j*16+d]
    float a = 0.f;
#pragma unroll 8
    for (int k = 0; k < KD; ++k) a += g_s[k] * W[k * JDIM + j * DCAP + t];
    o_s[t] = a;
  }
  __syncthreads();
  if (pass < 2) {
    // V[b][j][k] = sum_d W[k][j*16+d] * o[j][d]; thread = k
    const float* wp = W + t * JDIM + j * DCAP;
    float a = 0.f;
#pragma unroll
    for (int d = 0; d < DCAP; ++d) a += wp[d] * o_s[d];
    Out[((size_t)(b * JCAP) + j) * KD + t] = a;
  } else if (t < DCAP) {
    float s2 = 0.f;
#pragma unroll
    for (int d = 0; d < DCAP; ++d) s2 += o_s[d] * o_s[d];
    const float sc = s2 / ((1.f + s2) * sqrtf(s2 + EPSQ));
    Out[(size_t)(b * JCAP + j) * DCAP + t] = o_s[t] * sc;
  }
}

// ---- K3/K5: routing pass: logits -> softmax_j -> G partials (global) ----
__global__ __launch_bounds__(256, 8) void f_route(const float* __restrict__ u,
                                                  const float* __restrict__ V,
                                                  float* __restrict__ Gp) {
  const int b = blockIdx.y, tile = blockIdx.x, t = threadIdx.x;
  const int w = t >> 6, l = t & 63;
  __shared__ __align__(16) float4 u4[TROW * 32];   // 16 KB, XOR-swizzled
  __shared__ __align__(16) float Cs[JCAP * TROW];  // 1.25 KB

  // (1) wave-local DMA: wave w stages u rows 8w..8w+7 (linear dest,
  //     inverse-swizzled per-lane source: logical col L lands at pos L^(r&7))
  {
    const float* ub = u + (((size_t)(b * NN + tile * TROW)) << 7);
#pragma unroll
    for (int p = 0; p < 4; ++p) {
      const int df = (w << 8) + (p << 6);          // wave-uniform f4 slot base
      const int s = df + l;
      const int r = s >> 5, pos = s & 31;
      const int L = pos ^ (r & 7);
      gload16(ub + (((size_t)r) << 7) + (L << 2), &u4[df]);
    }
  }
  asm volatile("s_waitcnt vmcnt(0)" ::: "memory");  // own-wave DMAs landed
  __builtin_amdgcn_sched_barrier(0);

  // (2) ph1: logits for OWN rows. rx = l>>3 (row), kq = l&7 (k-eighth).
  //     u from swizzled LDS; V from GLOBAL (L2-hot). Full k-reduce in-wave
  //     (shfl_xor 1,2,4); lane kq==0 softmaxes in-register, writes Cs.
  {
    const int rx = l >> 3, kq = l & 7;
    const int r = (w << 3) + rx;
    float4 ur[4];
#pragma unroll
    for (int c = 0; c < 4; ++c) ur[c] = u4[(r << 5) + ((c * 8 + kq) ^ rx)];
    const float* vb = V + (((size_t)(b * JCAP)) << 7);
    float acc[JCAP];
#pragma unroll
    for (int j = 0; j < JCAP; ++j) acc[j] = 0.f;
#pragma unroll
    for (int c = 0; c < 4; ++c) {
      const int vo = (c * 8 + kq) << 2;
#pragma unroll
      for (int j = 0; j < JCAP; ++j) {
        const float4 vv = *(const float4*)(vb + (j << 7) + vo);
        acc[j] += ur[c].x * vv.x + ur[c].y * vv.y + ur[c].z * vv.z + ur[c].w * vv.w;
      }
    }
#pragma unroll
    for (int j = 0; j < JCAP; ++j) {
      acc[j] += __shfl_xor(acc[j], 1, 64);
      acc[j] += __shfl_xor(acc[j], 2, 64);
      acc[j] += __shfl_xor(acc[j], 4, 64);
    }
    if (kq == 0) {
      float m = acc[0];
#pragma unroll
      for (int j = 1; j < JCAP; ++j) m = fmaxf(m, acc[j]);
      float ss = 0.f;
#pragma unroll
      for (int j = 0; j < JCAP; ++j) { acc[j] = __expf(acc[j] - m); ss += acc[j]; }
      const float inv = 1.f / ss;
#pragma unroll
      for (int j = 0; j < JCAP; ++j) Cs[j * TROW + r] = acc[j] * inv;
    }
  }
  __syncthreads();   // Cs + all waves' u4 rows visible

  // (3) ph2: G[j][k] = sum_r c[j][r]*u[r][k]. Wave owns j-subset; lane =
  //     (c4 = l&31 column, h = l>>5 row-half). u: b128 reads (full-row
  //     wavefronts, conflict-free); Cs: 1 b128 per (j, 4 rows); half-fold
  //     via 12 shfl; G stored directly to global (coalesced b128).
  {
    const int j0 = (w < 2) ? 3 * w : 2 * w + 2;     // {0,3,6,8}
    const int jn = (w < 2) ? 3 : 2;                 // {3,3,2,2}
    const int c4 = l & 31, h = l >> 5;
    const int c4h = c4 ^ (h << 2);                  // XOR bits disjoint from i
    float4 g[3];
#pragma unroll
    for (int jj = 0; jj < 3; ++jj) g[jj] = make_float4(0.f, 0.f, 0.f, 0.f);
#pragma unroll
    for (int o = 0; o < 4; ++o) {                   // octave = 8 rows
      float4 uo[4];
#pragma unroll
      for (int i = 0; i < 4; ++i) {                 // r = o*8 + h*4 + i
        const int r = (o << 3) + (h << 2) + i;
        uo[i] = u4[(r << 5) + (c4h ^ i)];
      }
#pragma unroll
      for (int jj = 0; jj < 3; ++jj) {
        if (jj < jn) {
          const float4 cs = *(const float4*)&Cs[(j0 + jj) * TROW + (o << 3) + (h << 2)];
          g[jj].x += cs.x * uo[0].x + cs.y * uo[1].x + cs.z * uo[2].x + cs.w * uo[3].x;
          g[jj].y += cs.x * uo[0].y + cs.y * uo[1].y + cs.z * uo[2].y + cs.w * uo[3].y;
          g[jj].z += cs.x * uo[0].z + cs.y * uo[1].z + cs.z * uo[2].z + cs.w * uo[3].z;
          g[jj].w += cs.x * uo[0].w + cs.y * uo[1].w + cs.z * uo[2].w + cs.w * uo[3].w;
        }
      }
    }
#pragma unroll
    for (int jj = 0; jj < 3; ++jj) {
      if (jj < jn) {
        g[jj].x += __shfl_xor(g[jj].x, 32, 64);
        g[jj].y += __shfl_xor(g[jj].y, 32, 64);
        g[jj].z += __shfl_xor(g[jj].z, 32, 64);
        g[jj].w += __shfl_xor(g[jj].w, 32, 64);
      }
    }
    if (h == 0) {
      float* gb = Gp + ((size_t)(b * NT + tile)) * JCAP * KD;
#pragma unroll
      for (int jj = 0; jj < 3; ++jj)
        if (jj < jn)
          *(float4*)&gb[(j0 + jj) * KD + (c4 << 2)] = g[jj];
    }
  }
}

extern "C" void kernel_launch(void* const* d_in, const int* in_sizes, int n_in,
                              void* d_out, int out_size, void* d_ws, size_t ws_size,
                              hipStream_t stream) {
  const float* u = (const float*)d_in[0];   // (64,2048,128) fp32
  const float* W = (const float*)d_in[1];   // (128,160) fp32
  float* out = (float*)d_out;               // (64,10,16) fp32
  float* ws  = (float*)d_ws;

  float* Gp = ws + WS_GP;   // Sp aliases this region (fold0 consumes it first)
  float* V  = ws + WS_V;
  f_iter0 <<<dim3(NT, BATCH), 256, 0, stream>>>(u, Gp);
  f_fold  <<<dim3(JCAP, BATCH), 128, 0, stream>>>(Gp, W, V, 0);
  f_route <<<dim3(NT, BATCH), 256, 0, stream>>>(u, V, Gp);
  f_fold  <<<dim3(JCAP, BATCH), 128, 0, stream>>>(Gp, W, V, 1);
  f_route <<<dim3(NT, BATCH), 256, 0, stream>>>(u, V, Gp);
  f_fold  <<<dim3(JCAP, BATCH), 128, 0, stream>>>(Gp, W, out, 2);
}

// Round 11
// 183.962 us; speedup vs baseline: 1.9667x; 1.9667x over previous
//
#include <hip/hip_runtime.h>
#include <math.h>

// Capsule dynamic routing, MI355X. Round 14: R13 minus the register strangle.
// R13 post-mortem: __launch_bounds__(256,8) forced VGPR=32 -> the ~55-reg
// working set spilled to scratch (WRITE_SIZE 270MB/dispatch, VALUBusy 10%,
// route 134us). Fix: __launch_bounds__(256,4) (budget 128, need ~55, no
// spill); LDS 17.25KB still allows 8 blocks/CU and <=64 VGPR still allows
// 8 waves/SIMD, so occupancy is unchanged -- only the spills go away.
// Structure unchanged from R13:
//   - V read from GLOBAL (L2-hot, 5KB/batch shared by 64 blocks).
//   - ph2 lane=(c4 column, row-half): u 16 b128, Cs 12 b128, 12-shfl fold,
//     G direct to global (coalesced b128).
//   - wave-local u staging + per-wave vmcnt gate; single barrier.
// Chain: iter0(Sp) -> fold0(V) -> route(Gp) -> fold1(V) -> route(Gp) -> fold2(out).

#define BATCH 64
#define NN    2048
#define KD    128
#define JCAP  10
#define DCAP  16
#define JDIM  160
#define EPSQ  1e-7f
#define NT    64      // tiles of TROW rows ; NT*TROW == NN
#define TROW  32

// ws layout (floats): Gp[64][64][10][128] @0 (Sp[64][64][128] aliases @0) ;
//                     V[64][10][128] @5242880
#define WS_GP 0
#define WS_V  (BATCH * NT * JCAP * KD)

__device__ __forceinline__ void gload16(const float* g, void* l) {
  __builtin_amdgcn_global_load_lds(
      (const __attribute__((address_space(1))) void*)g,
      (__attribute__((address_space(3))) void*)l, 16, 0, 0);
}

// ---- K1: per-tile colsum partials Sp[b][tile][k] ----
__global__ __launch_bounds__(256) void f_iter0(const float* __restrict__ u,
                                               float* __restrict__ Sp) {
  const int b = blockIdx.y, tile = blockIdx.x, t = threadIdx.x;
  __shared__ __align__(16) float4 red[256];
  const int c = t & 31, rg = t >> 5;        // 8 row-groups x 4 rows
  const float* p = u + (((size_t)(b * NN + tile * TROW + rg * 4)) << 7) + (c << 2);
  float4 a = make_float4(0.f, 0.f, 0.f, 0.f);
#pragma unroll
  for (int r = 0; r < 4; ++r) {
    const float4 w4 = *(const float4*)(p + ((size_t)r << 7));
    a.x += w4.x; a.y += w4.y; a.z += w4.z; a.w += w4.w;
  }
  red[t] = a;
  __syncthreads();
  if (t < 32) {
    float4 s4 = red[t];
#pragma unroll
    for (int g = 1; g < 8; ++g) {
      const float4 w4 = red[g * 32 + t];
      s4.x += w4.x; s4.y += w4.y; s4.z += w4.z; s4.w += w4.w;
    }
    *(float4*)&Sp[(size_t)(b * NT + tile) * KD + t * 4] = s4;
  }
}

// ---- K2/K4/K6: block (j,b): fold partials -> o[j] -> {V | squash-out} ----
// pass0: In=Sp (x0.1) ; pass1: In=Gp ; both write V. pass2: In=Gp, write out.
__global__ __launch_bounds__(128) void f_fold(const float* __restrict__ In,
                                              const float* __restrict__ W,
                                              float* __restrict__ Out, int pass) {
  const int j = blockIdx.x, b = blockIdx.y, t = threadIdx.x;
  __shared__ float g_s[KD];
  __shared__ float o_s[DCAP];
  if (pass == 0) {
    const float* p = In + (size_t)b * NT * KD + t;        // Sp[b][tl][t]
    float s = 0.f;
#pragma unroll 8
    for (int tl = 0; tl < NT; ++tl) s += p[(size_t)tl * KD];
    g_s[t] = s * 0.1f;
  } else {
    const float* p = In + ((size_t)(b * NT) * JCAP + j) * KD + t;  // Gp[b][tl][j][t]
    float s = 0.f;
#pragma unroll 8
    for (int tl = 0; tl < NT; ++tl) s += p[(size_t)tl * JCAP * KD];
    g_s[t] = s;
  }
  __syncthreads();
  if (t < DCAP) {
    // o[j][d] = sum_k G[j][k] * W[k][j*16+d]
    float a = 0.f;
#pragma unroll 8
    for (int k = 0; k < KD; ++k) a += g_s[k] * W[k * JDIM + j * DCAP + t];
    o_s[t] = a;
  }
  __syncthreads();
  if (pass < 2) {
    // V[b][j][k] = sum_d W[k][j*16+d] * o[j][d]; thread = k
    const float* wp = W + t * JDIM + j * DCAP;
    float a = 0.f;
#pragma unroll
    for (int d = 0; d < DCAP; ++d) a += wp[d] * o_s[d];
    Out[((size_t)(b * JCAP) + j) * KD + t] = a;
  } else if (t < DCAP) {
    float s2 = 0.f;
#pragma unroll
    for (int d = 0; d < DCAP; ++d) s2 += o_s[d] * o_s[d];
    const float sc = s2 / ((1.f + s2) * sqrtf(s2 + EPSQ));
    Out[(size_t)(b * JCAP + j) * DCAP + t] = o_s[t] * sc;
  }
}

// ---- K3/K5: routing pass: logits -> softmax_j -> G partials (global) ----
__global__ __launch_bounds__(256, 4) void f_route(const float* __restrict__ u,
                                                  const float* __restrict__ V,
                                                  float* __restrict__ Gp) {
  const int b = blockIdx.y, tile = blockIdx.x, t = threadIdx.x;
  const int w = t >> 6, l = t & 63;
  __shared__ __align__(16) float4 u4[TROW * 32];   // 16 KB, XOR-swizzled
  __shared__ __align__(16) float Cs[JCAP * TROW];  // 1.25 KB

  // (1) wave-local DMA: wave w stages u rows 8w..8w+7 (linear dest,
  //     inverse-swizzled per-lane source: logical col L lands at pos L^(r&7))
  {
    const float* ub = u + (((size_t)(b * NN + tile * TROW)) << 7);
#pragma unroll
    for (int p = 0; p < 4; ++p) {
      const int df = (w << 8) + (p << 6);          // wave-uniform f4 slot base
      const int s = df + l;
      const int r = s >> 5, pos = s & 31;
      const int L = pos ^ (r & 7);
      gload16(ub + (((size_t)r) << 7) + (L << 2), &u4[df]);
    }
  }
  asm volatile("s_waitcnt vmcnt(0)" ::: "memory");  // own-wave DMAs landed
  __builtin_amdgcn_sched_barrier(0);

  // (2) ph1: logits for OWN rows. rx = l>>3 (row), kq = l&7 (k-eighth).
  //     u from swizzled LDS; V from GLOBAL (L2-hot). Full k-reduce in-wave
  //     (shfl_xor 1,2,4); lane kq==0 softmaxes in-register, writes Cs.
  {
    const int rx = l >> 3, kq = l & 7;
    const int r = (w << 3) + rx;
    float4 ur[4];
#pragma unroll
    for (int c = 0; c < 4; ++c) ur[c] = u4[(r << 5) + ((c * 8 + kq) ^ rx)];
    const float* vb = V + (((size_t)(b * JCAP)) << 7);
    float acc[JCAP];
#pragma unroll
    for (int j = 0; j < JCAP; ++j) acc[j] = 0.f;
#pragma unroll
    for (int c = 0; c < 4; ++c) {
      const int vo = (c * 8 + kq) << 2;
#pragma unroll
      for (int j = 0; j < JCAP; ++j) {
        const float4 vv = *(const float4*)(vb + (j << 7) + vo);
        acc[j] += ur[c].x * vv.x + ur[c].y * vv.y + ur[c].z * vv.z + ur[c].w * vv.w;
      }
    }
#pragma unroll
    for (int j = 0; j < JCAP; ++j) {
      acc[j] += __shfl_xor(acc[j], 1, 64);
      acc[j] += __shfl_xor(acc[j], 2, 64);
      acc[j] += __shfl_xor(acc[j], 4, 64);
    }
    if (kq == 0) {
      float m = acc[0];
#pragma unroll
      for (int j = 1; j < JCAP; ++j) m = fmaxf(m, acc[j]);
      float ss = 0.f;
#pragma unroll
      for (int j = 0; j < JCAP; ++j) { acc[j] = __expf(acc[j] - m); ss += acc[j]; }
      const float inv = 1.f / ss;
#pragma unroll
      for (int j = 0; j < JCAP; ++j) Cs[j * TROW + r] = acc[j] * inv;
    }
  }
  __syncthreads();   // Cs + all waves' u4 rows visible

  // (3) ph2: G[j][k] = sum_r c[j][r]*u[r][k]. Wave owns j-subset; lane =
  //     (c4 = l&31 column, h = l>>5 row-half). u: b128 reads (full-row
  //     wavefronts, conflict-free); Cs: 1 b128 per (j, 4 rows); half-fold
  //     via 12 shfl; G stored directly to global (coalesced b128).
  {
    const int j0 = (w < 2) ? 3 * w : 2 * w + 2;     // {0,3,6,8}
    const int jn = (w < 2) ? 3 : 2;                 // {3,3,2,2}
    const int c4 = l & 31, h = l >> 5;
    const int c4h = c4 ^ (h << 2);                  // XOR bits disjoint from i
    float4 g[3];
#pragma unroll
    for (int jj = 0; jj < 3; ++jj) g[jj] = make_float4(0.f, 0.f, 0.f, 0.f);
#pragma unroll
    for (int o = 0; o < 4; ++o) {                   // octave = 8 rows
      float4 uo[4];
#pragma unroll
      for (int i = 0; i < 4; ++i) {                 // r = o*8 + h*4 + i
        const int r = (o << 3) + (h << 2) + i;
        uo[i] = u4[(r << 5) + (c4h ^ i)];
      }
#pragma unroll
      for (int jj = 0; jj < 3; ++jj) {
        if (jj < jn) {
          const float4 cs = *(const float4*)&Cs[(j0 + jj) * TROW + (o << 3) + (h << 2)];
          g[jj].x += cs.x * uo[0].x + cs.y * uo[1].x + cs.z * uo[2].x + cs.w * uo[3].x;
          g[jj].y += cs.x * uo[0].y + cs.y * uo[1].y + cs.z * uo[2].y + cs.w * uo[3].y;
          g[jj].z += cs.x * uo[0].z + cs.y * uo[1].z + cs.z * uo[2].z + cs.w * uo[3].z;
          g[jj].w += cs.x * uo[0].w + cs.y * uo[1].w + cs.z * uo[2].w + cs.w * uo[3].w;
        }
      }
    }
#pragma unroll
    for (int jj = 0; jj < 3; ++jj) {
      if (jj < jn) {
        g[jj].x += __shfl_xor(g[jj].x, 32, 64);
        g[jj].y += __shfl_xor(g[jj].y, 32, 64);
        g[jj].z += __shfl_xor(g[jj].z, 32, 64);
        g[jj].w += __shfl_xor(g[jj].w, 32, 64);
      }
    }
    if (h == 0) {
      float* gb = Gp + ((size_t)(b * NT + tile)) * JCAP * KD;
#pragma unroll
      for (int jj = 0; jj < 3; ++jj)
        if (jj < jn)
          *(float4*)&gb[(j0 + jj) * KD + (c4 << 2)] = g[jj];
    }
  }
}

extern "C" void kernel_launch(void* const* d_in, const int* in_sizes, int n_in,
                              void* d_out, int out_size, void* d_ws, size_t ws_size,
                              hipStream_t stream) {
  const float* u = (const float*)d_in[0];   // (64,2048,128) fp32
  const float* W = (const float*)d_in[1];   // (128,160) fp32
  float* out = (float*)d_out;               // (64,10,16) fp32
  float* ws  = (float*)d_ws;

  float* Gp = ws + WS_GP;   // Sp aliases this region (fold0 consumes it first)
  float* V  = ws + WS_V;
  f_iter0 <<<dim3(NT, BATCH), 256, 0, stream>>>(u, Gp);
  f_fold  <<<dim3(JCAP, BATCH), 128, 0, stream>>>(Gp, W, V, 0);
  f_route <<<dim3(NT, BATCH), 256, 0, stream>>>(u, V, Gp);
  f_fold  <<<dim3(JCAP, BATCH), 128, 0, stream>>>(Gp, W, V, 1);
  f_route <<<dim3(NT, BATCH), 256, 0, stream>>>(u, V, Gp);
  f_fold  <<<dim3(JCAP, BATCH), 128, 0, stream>>>(Gp, W, out, 2);
}